// Round 1
// baseline (729.738 us; speedup 1.0000x reference)
//
#include <hip/hip_runtime.h>
#include <hip/hip_bf16.h>

#define SS 2048
#define DD 128
#define HH 16
#define BB 2
#define HD 2048   // H*D
#define BS 4096   // B*S

typedef __attribute__((ext_vector_type(4))) float f32x4;
typedef __attribute__((ext_vector_type(8))) short s16x8;

__device__ __forceinline__ short f2bf(float f) {
    union { __hip_bfloat16 h; short s; } u;
    u.h = __float2bfloat16(f);
    return u.s;
}
__device__ __forceinline__ float bf2f(short s) {
    union { unsigned u; float f; } w;
    w.u = ((unsigned)(unsigned short)s) << 16;
    return w.f;
}

// ---- prep: transpose+convert Wq/Wk/Wv [128][2048] -> WT bf16 [2048][128]
__global__ void prep_wt(const float* __restrict__ Wq, const float* __restrict__ Wk,
                        const float* __restrict__ Wv, short* __restrict__ WTq,
                        short* __restrict__ WTk, short* __restrict__ WTv) {
    int c = blockIdx.x;            // 0..2047
    int z = blockIdx.y;            // 0..2
    const float* W = (z==0) ? Wq : (z==1) ? Wk : Wv;
    short* WT      = (z==0) ? WTq : (z==1) ? WTk : WTv;
    int k = threadIdx.x;           // 0..127
    WT[c*DD + k] = f2bf(W[k*HD + c]);
}

// ---- prep: Wf [2048][128] -> WfT hi/lo bf16 [128][2048]
__global__ void prep_wf(const float* __restrict__ Wf, short* __restrict__ Whi,
                        short* __restrict__ Wlo) {
    int j = blockIdx.x;            // 0..127
    for (int k = threadIdx.x; k < HD; k += blockDim.x) {
        float v = Wf[k*DD + j];
        short hb = f2bf(v);
        Whi[j*HD + k] = hb;
        Wlo[j*HD + k] = f2bf(v - bf2f(hb));
    }
}

// ---- QKV projections. z=0: q -> Yq (row-major [4096][2048] bf16)
//                       z=1: k -> Yk
//                       z=2: v -> Vt transposed per-head: Vt[((b*16+h)*128+d)*2048 + s]
__global__ __launch_bounds__(256) void proj_kernel(
    const float* __restrict__ Xq, const float* __restrict__ Xk, const float* __restrict__ Xv,
    const short* __restrict__ WTq, const short* __restrict__ WTk, const short* __restrict__ WTv,
    const float* __restrict__ bq, const float* __restrict__ bk, const float* __restrict__ bv,
    short* __restrict__ Yq, short* __restrict__ Yk, short* __restrict__ Vt)
{
    int z = blockIdx.y;
    const float* X  = (z==0) ? Xq  : (z==1) ? Xk  : Xv;
    const short* WT = (z==0) ? WTq : (z==1) ? WTk : WTv;
    const float* bias = (z==0) ? bq : (z==1) ? bk : bv;

    int wave = threadIdx.x >> 6;
    int lane = threadIdx.x & 63;
    int lr = lane & 15, lg = lane >> 4;
    int tile = blockIdx.x * 4 + wave;     // 0..32767
    int tm = tile >> 7;                   // row tile 0..255
    int tn = tile & 127;                  // col tile 0..127
    int row0 = tm * 16, col0 = tn * 16;

    // A frags: X[row0+lr][lg*8 + c*32 + j]  (fp32 -> bf16)
    s16x8 afr[4];
    const float* xrow = X + (size_t)(row0 + lr) * DD + lg * 8;
    #pragma unroll
    for (int c = 0; c < 4; ++c) {
        #pragma unroll
        for (int j = 0; j < 8; ++j) afr[c][j] = f2bf(xrow[c*32 + j]);
    }
    // B frags: WT[col0+lr][lg*8 + c*32 ..] contiguous bf16
    f32x4 acc = {0.f, 0.f, 0.f, 0.f};
    const short* wrow = WT + (size_t)(col0 + lr) * DD + lg * 8;
    #pragma unroll
    for (int c = 0; c < 4; ++c) {
        s16x8 bfr = *reinterpret_cast<const s16x8*>(wrow + c*32);
        acc = __builtin_amdgcn_mfma_f32_16x16x32_bf16(afr[c], bfr, acc, 0, 0, 0);
    }
    float bcol = bias[col0 + lr];

    if (z < 2) {
        short* Y = (z==0) ? Yq : Yk;
        #pragma unroll
        for (int r = 0; r < 4; ++r) {
            int row = row0 + lg*4 + r;
            Y[(size_t)row * HD + col0 + lr] = f2bf(acc[r] + bcol);
        }
    } else {
        #pragma unroll
        for (int r = 0; r < 4; ++r) {
            int row = row0 + lg*4 + r;           // 0..4095
            int bb = row >> 11;                  // batch
            int f  = (row & 2047) * HD + col0 + lr;  // within-batch flat idx
            int hh = f >> 18;                    // /(S*D)=262144
            int rem = f & 262143;
            int s = rem >> 7, d = rem & 127;
            Vt[((size_t)((bb*HH + hh)*DD + d)) * SS + s] = f2bf(acc[r] + bcol);
        }
    }
}

// ---- fused attention: per wave one (b,h,16-row q-tile), flash-style online softmax
__global__ __launch_bounds__(256) void attn_kernel(
    const short* __restrict__ Yq, const short* __restrict__ Yk, const short* __restrict__ Vt,
    const float* __restrict__ mask, float* __restrict__ Aout)
{
    __shared__ alignas(16) short plds[4][16][32];
    int wave = threadIdx.x >> 6, lane = threadIdx.x & 63;
    int lr = lane & 15, lg = lane >> 4;
    int qt = blockIdx.x;       // 0..127
    int hg = blockIdx.y;       // 0..3
    int b  = blockIdx.z;       // 0..1
    int h  = hg * 4 + wave;

    const short* Qb = Yq + (size_t)(b*HH + h) * (SS*DD);
    const short* Kb = Yk + (size_t)(b*HH + h) * (SS*DD);
    const short* Vb = Vt + (size_t)(b*HH + h) * (SS*DD);
    const float* Mb = mask + (size_t)b * SS * SS;
    int q0 = qt * 16;

    // Q fragments (held for whole loop)
    s16x8 qf[4];
    const short* qrow = Qb + (size_t)(q0 + lr) * DD + lg * 8;
    #pragma unroll
    for (int c = 0; c < 4; ++c) qf[c] = *reinterpret_cast<const s16x8*>(qrow + c*32);

    f32x4 o[8];
    #pragma unroll
    for (int t = 0; t < 8; ++t) o[t] = (f32x4){0.f, 0.f, 0.f, 0.f};
    float mrun[4] = {-1e30f, -1e30f, -1e30f, -1e30f};
    float lsum[4] = {0.f, 0.f, 0.f, 0.f};
    const float rs = 0.022097086912079608f;   // 1/sqrt(2048)

    for (int kt = 0; kt < SS/32; ++kt) {
        int kp0 = kt * 32;
        // two 16x16 score tiles (cols kp0..+15, kp0+16..+31)
        f32x4 st[2];
        #pragma unroll
        for (int t = 0; t < 2; ++t) {
            f32x4 acc = {0.f, 0.f, 0.f, 0.f};
            const short* krow = Kb + (size_t)(kp0 + t*16 + lr) * DD + lg * 8;
            #pragma unroll
            for (int c = 0; c < 4; ++c) {
                s16x8 kf = *reinterpret_cast<const s16x8*>(krow + c*32);
                acc = __builtin_amdgcn_mfma_f32_16x16x32_bf16(qf[c], kf, acc, 0, 0, 0);
            }
            #pragma unroll
            for (int r = 0; r < 4; ++r) {
                float mv = Mb[(size_t)(q0 + lg*4 + r) * SS + kp0 + t*16 + lr];
                st[t][r] = acc[r] * rs * mv;
            }
        }
        // online softmax update (rows live in 16-lane groups)
        #pragma unroll
        for (int r = 0; r < 4; ++r) {
            float tmax = fmaxf(st[0][r], st[1][r]);
            #pragma unroll
            for (int x = 8; x >= 1; x >>= 1) tmax = fmaxf(tmax, __shfl_xor(tmax, x, 64));
            float nm = fmaxf(mrun[r], tmax);
            float corr = __expf(mrun[r] - nm);
            float p0 = __expf(st[0][r] - nm);
            float p1 = __expf(st[1][r] - nm);
            float psum = p0 + p1;
            #pragma unroll
            for (int x = 8; x >= 1; x >>= 1) psum += __shfl_xor(psum, x, 64);
            lsum[r] = lsum[r] * corr + psum;
            mrun[r] = nm;
            st[0][r] = p0; st[1][r] = p1;
            #pragma unroll
            for (int t = 0; t < 8; ++t) o[t][r] *= corr;
        }
        // P -> LDS (D-frag layout) then read back as A-frag layout
        __syncthreads();
        #pragma unroll
        for (int r = 0; r < 4; ++r) {
            plds[wave][lg*4 + r][lr]      = f2bf(st[0][r]);
            plds[wave][lg*4 + r][16 + lr] = f2bf(st[1][r]);
        }
        __syncthreads();
        s16x8 pf = *reinterpret_cast<const s16x8*>(&plds[wave][lr][lg*8]);
        // PV: o[dt] += P(16x32) * V(32x16), V from transposed layout (contiguous)
        #pragma unroll
        for (int t = 0; t < 8; ++t) {
            const short* vrow = Vb + (size_t)(t*16 + lr) * SS + kp0 + lg*8;
            s16x8 vf = *reinterpret_cast<const s16x8*>(vrow);
            o[t] = __builtin_amdgcn_mfma_f32_16x16x32_bf16(pf, vf, o[t], 0, 0, 0);
        }
    }

    float* orow = Aout + ((size_t)(b*HH + h) * SS + q0) * DD;
    #pragma unroll
    for (int r = 0; r < 4; ++r) {
        float inv = 1.0f / lsum[r];
        #pragma unroll
        for (int t = 0; t < 8; ++t) {
            orow[(size_t)(lg*4 + r) * DD + t*16 + lr] = o[t][r] * inv;
        }
    }
}

// ---- final GEMM: out[4096][128] = A[4096][2048] @ Wf + bf, hi/lo bf16 split (~fp32 acc)
__global__ __launch_bounds__(256) void final_gemm(
    const float* __restrict__ A, const short* __restrict__ Whi, const short* __restrict__ Wlo,
    const float* __restrict__ bfv, float* __restrict__ out)
{
    int wave = threadIdx.x >> 6, lane = threadIdx.x & 63;
    int lr = lane & 15, lg = lane >> 4;
    int tile = blockIdx.x * 4 + wave;   // 0..2047
    int tm = tile >> 3;                 // 0..255
    int tn = tile & 7;                  // 0..7
    int row0 = tm * 16, col0 = tn * 16;

    f32x4 acc = {0.f, 0.f, 0.f, 0.f};
    const float* arow = A + (size_t)(row0 + lr) * HD + lg * 8;
    const short* whrow = Whi + (size_t)(col0 + lr) * HD + lg * 8;
    const short* wlrow = Wlo + (size_t)(col0 + lr) * HD + lg * 8;
    for (int kc = 0; kc < HD/32; ++kc) {
        s16x8 ah, al;
        #pragma unroll
        for (int j = 0; j < 8; ++j) {
            float v = arow[kc*32 + j];
            short hb = f2bf(v);
            ah[j] = hb;
            al[j] = f2bf(v - bf2f(hb));
        }
        s16x8 bh = *reinterpret_cast<const s16x8*>(whrow + kc*32);
        s16x8 bl = *reinterpret_cast<const s16x8*>(wlrow + kc*32);
        acc = __builtin_amdgcn_mfma_f32_16x16x32_bf16(ah, bh, acc, 0, 0, 0);
        acc = __builtin_amdgcn_mfma_f32_16x16x32_bf16(ah, bl, acc, 0, 0, 0);
        acc = __builtin_amdgcn_mfma_f32_16x16x32_bf16(al, bh, acc, 0, 0, 0);
    }
    float bc = bfv[col0 + lr];
    #pragma unroll
    for (int r = 0; r < 4; ++r) {
        out[(size_t)(row0 + lg*4 + r) * DD + col0 + lr] = acc[r] + bc;
    }
}

extern "C" void kernel_launch(void* const* d_in, const int* in_sizes, int n_in,
                              void* d_out, int out_size, void* d_ws, size_t ws_size,
                              hipStream_t stream) {
    const float* v    = (const float*)d_in[0];
    const float* k    = (const float*)d_in[1];
    const float* q    = (const float*)d_in[2];
    const float* mask = (const float*)d_in[3];
    const float* Wq   = (const float*)d_in[4];
    const float* bq   = (const float*)d_in[5];
    const float* Wk   = (const float*)d_in[6];
    const float* bk   = (const float*)d_in[7];
    const float* Wv   = (const float*)d_in[8];
    const float* bv   = (const float*)d_in[9];
    const float* Wf   = (const float*)d_in[10];
    const float* bf   = (const float*)d_in[11];
    float* out = (float*)d_out;

    char* ws = (char*)d_ws;
    size_t off = 0;
    short* Yq   = (short*)(ws + off); off += (size_t)BS * HD * 2;   // 16 MB
    short* Yk   = (short*)(ws + off); off += (size_t)BS * HD * 2;   // 16 MB
    short* Vt   = (short*)(ws + off); off += (size_t)BS * HD * 2;   // 16 MB
    float* Aout = (float*)(ws + off); off += (size_t)BS * HD * 4;   // 33.5 MB
    short* WTq  = (short*)(ws + off); off += (size_t)HD * DD * 2;
    short* WTk  = (short*)(ws + off); off += (size_t)HD * DD * 2;
    short* WTv  = (short*)(ws + off); off += (size_t)HD * DD * 2;
    short* Wfhi = (short*)(ws + off); off += (size_t)DD * HD * 2;
    short* Wflo = (short*)(ws + off); off += (size_t)DD * HD * 2;

    prep_wt<<<dim3(2048, 3), 128, 0, stream>>>(Wq, Wk, Wv, WTq, WTk, WTv);
    prep_wf<<<dim3(128), 256, 0, stream>>>(Wf, Wfhi, Wflo);
    proj_kernel<<<dim3(8192, 3), 256, 0, stream>>>(q, k, v, WTq, WTk, WTv,
                                                   bq, bk, bv, Yq, Yk, Vt);
    attn_kernel<<<dim3(128, 4, 2), 256, 0, stream>>>(Yq, Yk, Vt, mask, Aout);
    final_gemm<<<dim3(512), 256, 0, stream>>>(Aout, Wfhi, Wflo, bf, out);
}

// Round 2
// 651.214 us; speedup vs baseline: 1.1206x; 1.1206x over previous
//
#include <hip/hip_runtime.h>
#include <hip/hip_bf16.h>

#define SS 2048
#define DD 128
#define HH 16
#define BB 2
#define HD 2048   // H*D
#define BS 4096   // B*S

typedef __attribute__((ext_vector_type(4))) float f32x4;
typedef __attribute__((ext_vector_type(8))) short s16x8;

__device__ __forceinline__ short f2bf(float f) {
    union { __hip_bfloat16 h; short s; } u;
    u.h = __float2bfloat16(f);
    return u.s;
}
__device__ __forceinline__ float bf2f(short s) {
    union { unsigned u; float f; } w;
    w.u = ((unsigned)(unsigned short)s) << 16;
    return w.f;
}

// ---- prep: transpose+convert Wq/Wk/Wv [128][2048] -> WT bf16 [2048][128]
__global__ void prep_wt(const float* __restrict__ Wq, const float* __restrict__ Wk,
                        const float* __restrict__ Wv, short* __restrict__ WTq,
                        short* __restrict__ WTk, short* __restrict__ WTv) {
    int c = blockIdx.x;            // 0..2047
    int z = blockIdx.y;            // 0..2
    const float* W = (z==0) ? Wq : (z==1) ? Wk : Wv;
    short* WT      = (z==0) ? WTq : (z==1) ? WTk : WTv;
    int k = threadIdx.x;           // 0..127
    WT[c*DD + k] = f2bf(W[k*HD + c]);
}

// ---- prep: Wf [2048][128] -> WfT hi/lo bf16 [128][2048]
__global__ void prep_wf(const float* __restrict__ Wf, short* __restrict__ Whi,
                        short* __restrict__ Wlo) {
    int j = blockIdx.x;            // 0..127
    for (int k = threadIdx.x; k < HD; k += blockDim.x) {
        float v = Wf[k*DD + j];
        short hb = f2bf(v);
        Whi[j*HD + k] = hb;
        Wlo[j*HD + k] = f2bf(v - bf2f(hb));
    }
}

// ---- QKV projections. Each wave: 16 rows x 64 cols (4 col-tiles share A-frags).
//      z=0: q -> Yq bf16 [4096][2048], PRE-SCALED by 1/sqrt(S)
//      z=1: k -> Yk
//      z=2: v -> Vt transposed per-head: Vt[((b*16+h)*128+d)*2048 + s]
__global__ __launch_bounds__(256) void proj_kernel(
    const float* __restrict__ Xq, const float* __restrict__ Xk, const float* __restrict__ Xv,
    const short* __restrict__ WTq, const short* __restrict__ WTk, const short* __restrict__ WTv,
    const float* __restrict__ bq, const float* __restrict__ bk, const float* __restrict__ bv,
    short* __restrict__ Yq, short* __restrict__ Yk, short* __restrict__ Vt)
{
    int z = blockIdx.y;
    const float* X  = (z==0) ? Xq  : (z==1) ? Xk  : Xv;
    const short* WT = (z==0) ? WTq : (z==1) ? WTk : WTv;
    const float* bias = (z==0) ? bq : (z==1) ? bk : bv;
    const float oscale = (z==0) ? 0.022097086912079608f : 1.0f;  // 1/sqrt(2048)

    int wave = threadIdx.x >> 6;
    int lane = threadIdx.x & 63;
    int lr = lane & 15, lg = lane >> 4;
    int bx = blockIdx.x;              // 0..2047
    int rb = bx >> 5;                 // 0..63
    int cb = bx & 31;                 // 0..31
    int row0 = rb * 64 + wave * 16;
    int col0 = cb * 64;

    // A frags: X[row0+lr][lg*8 + c*32 + j]  (fp32 -> bf16), reused for 4 col-tiles
    s16x8 afr[4];
    const float* xrow = X + (size_t)(row0 + lr) * DD + lg * 8;
    #pragma unroll
    for (int c = 0; c < 4; ++c) {
        #pragma unroll
        for (int j = 0; j < 8; ++j) afr[c][j] = f2bf(xrow[c*32 + j]);
    }

    f32x4 acc[4];
    #pragma unroll
    for (int tn2 = 0; tn2 < 4; ++tn2) {
        acc[tn2] = (f32x4){0.f, 0.f, 0.f, 0.f};
        const short* wrow = WT + (size_t)(col0 + tn2*16 + lr) * DD + lg * 8;
        #pragma unroll
        for (int c = 0; c < 4; ++c) {
            s16x8 bfr = *reinterpret_cast<const s16x8*>(wrow + c*32);
            acc[tn2] = __builtin_amdgcn_mfma_f32_16x16x32_bf16(afr[c], bfr, acc[tn2], 0, 0, 0);
        }
    }

    if (z < 2) {
        short* Y = (z==0) ? Yq : Yk;
        #pragma unroll
        for (int tn2 = 0; tn2 < 4; ++tn2) {
            float bcol = bias[col0 + tn2*16 + lr];
            #pragma unroll
            for (int r = 0; r < 4; ++r) {
                int row = row0 + lg*4 + r;
                Y[(size_t)row * HD + col0 + tn2*16 + lr] = f2bf((acc[tn2][r] + bcol) * oscale);
            }
        }
    } else {
        #pragma unroll
        for (int tn2 = 0; tn2 < 4; ++tn2) {
            float bcol = bias[col0 + tn2*16 + lr];
            #pragma unroll
            for (int r = 0; r < 4; ++r) {
                int row = row0 + lg*4 + r;               // 0..4095
                int bb = row >> 11;                      // batch
                int f  = (row & 2047) * HD + col0 + tn2*16 + lr;
                int hh = f >> 18;                        // /(S*D)
                int rem = f & 262143;
                int s = rem >> 7, d = rem & 127;
                Vt[((size_t)((bb*HH + hh)*DD + d)) * SS + s] = f2bf(acc[tn2][r] + bcol);
            }
        }
    }
}

// ---- fused attention: per wave one (b,h,16-row q-tile), KVBLK=64, NO barriers,
//      per-wave swizzled LDS for the P D-frag -> A-frag relayout.
__global__ __launch_bounds__(256) void attn_kernel(
    const short* __restrict__ Yq, const short* __restrict__ Yk, const short* __restrict__ Vt,
    const float* __restrict__ mask, float* __restrict__ Aout)
{
    __shared__ alignas(16) char plds[4][16 * 128];   // per-wave 16 rows x 128 B (64 bf16)
    int wave = threadIdx.x >> 6, lane = threadIdx.x & 63;
    int lr = lane & 15, lg = lane >> 4;
    int qt = blockIdx.x;       // 0..127
    int hg = blockIdx.y;       // 0..3
    int b  = blockIdx.z;       // 0..1
    int h  = hg * 4 + wave;

    const short* Qb = Yq + (size_t)(b*HH + h) * (SS*DD);
    const short* Kb = Yk + (size_t)(b*HH + h) * (SS*DD);
    const short* Vb = Vt + (size_t)(b*HH + h) * (SS*DD);
    int q0 = qt * 16;
    const float* Mb = mask + (size_t)b * SS * SS + (size_t)(q0 + lg*4) * SS;

    // Q fragments (held for whole loop); Yq is pre-scaled by 1/sqrt(S)
    s16x8 qf[4];
    const short* qrow = Qb + (size_t)(q0 + lr) * DD + lg * 8;
    #pragma unroll
    for (int c = 0; c < 4; ++c) qf[c] = *reinterpret_cast<const s16x8*>(qrow + c*32);

    f32x4 o[8];
    #pragma unroll
    for (int t = 0; t < 8; ++t) o[t] = (f32x4){0.f, 0.f, 0.f, 0.f};
    float mrun[4] = {-1e30f, -1e30f, -1e30f, -1e30f};
    float lsum[4] = {0.f, 0.f, 0.f, 0.f};

    char* pl = plds[wave];
    const int swr = (lr & 7) << 4;     // read-side swizzle (row = lr)

    for (int kt = 0; kt < SS/64; ++kt) {
        int kp0 = kt * 64;
        // mask loads (issued early, consumed after MFMAs)
        float mv[4][4];
        #pragma unroll
        for (int t = 0; t < 4; ++t)
            #pragma unroll
            for (int r = 0; r < 4; ++r)
                mv[t][r] = Mb[(size_t)r * SS + kp0 + t*16 + lr];

        // QK^T: four 16x16 score tiles
        f32x4 st[4];
        #pragma unroll
        for (int t = 0; t < 4; ++t) {
            f32x4 acc = {0.f, 0.f, 0.f, 0.f};
            const short* krow = Kb + (size_t)(kp0 + t*16 + lr) * DD + lg * 8;
            #pragma unroll
            for (int c = 0; c < 4; ++c) {
                s16x8 kf = *reinterpret_cast<const s16x8*>(krow + c*32);
                acc = __builtin_amdgcn_mfma_f32_16x16x32_bf16(qf[c], kf, acc, 0, 0, 0);
            }
            #pragma unroll
            for (int r = 0; r < 4; ++r) st[t][r] = acc[r] * mv[t][r];
        }

        // online softmax, one reduce per 64 cols
        float corr[4];
        #pragma unroll
        for (int r = 0; r < 4; ++r) {
            float tmax = fmaxf(fmaxf(st[0][r], st[1][r]), fmaxf(st[2][r], st[3][r]));
            #pragma unroll
            for (int x = 8; x >= 1; x >>= 1) tmax = fmaxf(tmax, __shfl_xor(tmax, x, 16));
            float nm = fmaxf(mrun[r], tmax);
            corr[r] = __expf(mrun[r] - nm);
            float psum = 0.f;
            #pragma unroll
            for (int t = 0; t < 4; ++t) { st[t][r] = __expf(st[t][r] - nm); psum += st[t][r]; }
            #pragma unroll
            for (int x = 8; x >= 1; x >>= 1) psum += __shfl_xor(psum, x, 16);
            lsum[r] = lsum[r] * corr[r] + psum;
            mrun[r] = nm;
        }
        #pragma unroll
        for (int dt = 0; dt < 8; ++dt)
            #pragma unroll
            for (int r = 0; r < 4; ++r) o[dt][r] *= corr[r];

        // P -> LDS (XOR-swizzled rows, per-wave buffer, no barrier needed)
        #pragma unroll
        for (int r = 0; r < 4; ++r) {
            int row = lg*4 + r;
            int sw = (row & 7) << 4;
            char* rp = pl + row * 128;
            #pragma unroll
            for (int t = 0; t < 4; ++t)
                *reinterpret_cast<short*>(rp + ((((t*16 + lr) << 1)) ^ sw)) = f2bf(st[t][r]);
        }
        asm volatile("s_waitcnt lgkmcnt(0)" ::: "memory");
        __builtin_amdgcn_sched_barrier(0);
        s16x8 pfr[2];
        #pragma unroll
        for (int c2 = 0; c2 < 2; ++c2)
            pfr[c2] = *reinterpret_cast<const s16x8*>(pl + lr*128 + ((c2*64 + lg*16) ^ swr));

        // PV: o[dt] += P(16x64) * V(64x16), V from transposed layout (contiguous)
        #pragma unroll
        for (int dt = 0; dt < 8; ++dt) {
            const short* vrow = Vb + (size_t)(dt*16 + lr) * SS + kp0 + lg*8;
            s16x8 vf0 = *reinterpret_cast<const s16x8*>(vrow);
            s16x8 vf1 = *reinterpret_cast<const s16x8*>(vrow + 32);
            o[dt] = __builtin_amdgcn_mfma_f32_16x16x32_bf16(pfr[0], vf0, o[dt], 0, 0, 0);
            o[dt] = __builtin_amdgcn_mfma_f32_16x16x32_bf16(pfr[1], vf1, o[dt], 0, 0, 0);
        }
    }

    float* orow = Aout + ((size_t)(b*HH + h) * SS + q0) * DD;
    #pragma unroll
    for (int r = 0; r < 4; ++r) {
        float inv = 1.0f / lsum[r];
        #pragma unroll
        for (int dt = 0; dt < 8; ++dt) {
            orow[(size_t)(lg*4 + r) * DD + dt*16 + lr] = o[dt][r] * inv;
        }
    }
}

// ---- final GEMM: out[4096][128] = A[4096][2048] @ Wf + bf, hi/lo bf16 split (~fp32 acc)
__global__ __launch_bounds__(256) void final_gemm(
    const float* __restrict__ A, const short* __restrict__ Whi, const short* __restrict__ Wlo,
    const float* __restrict__ bfv, float* __restrict__ out)
{
    int wave = threadIdx.x >> 6, lane = threadIdx.x & 63;
    int lr = lane & 15, lg = lane >> 4;
    int tile = blockIdx.x * 4 + wave;   // 0..2047
    int tm = tile >> 3;                 // 0..255
    int tn = tile & 7;                  // 0..7
    int row0 = tm * 16, col0 = tn * 16;

    f32x4 acc = {0.f, 0.f, 0.f, 0.f};
    const float* arow = A + (size_t)(row0 + lr) * HD + lg * 8;
    const short* whrow = Whi + (size_t)(col0 + lr) * HD + lg * 8;
    const short* wlrow = Wlo + (size_t)(col0 + lr) * HD + lg * 8;
    for (int kc = 0; kc < HD/32; ++kc) {
        s16x8 ah, al;
        #pragma unroll
        for (int j = 0; j < 8; ++j) {
            float v = arow[kc*32 + j];
            short hb = f2bf(v);
            ah[j] = hb;
            al[j] = f2bf(v - bf2f(hb));
        }
        s16x8 bh = *reinterpret_cast<const s16x8*>(whrow + kc*32);
        s16x8 bl = *reinterpret_cast<const s16x8*>(wlrow + kc*32);
        acc = __builtin_amdgcn_mfma_f32_16x16x32_bf16(ah, bh, acc, 0, 0, 0);
        acc = __builtin_amdgcn_mfma_f32_16x16x32_bf16(ah, bl, acc, 0, 0, 0);
        acc = __builtin_amdgcn_mfma_f32_16x16x32_bf16(al, bh, acc, 0, 0, 0);
    }
    float bc = bfv[col0 + lr];
    #pragma unroll
    for (int r = 0; r < 4; ++r) {
        out[(size_t)(row0 + lg*4 + r) * DD + col0 + lr] = acc[r] + bc;
    }
}

extern "C" void kernel_launch(void* const* d_in, const int* in_sizes, int n_in,
                              void* d_out, int out_size, void* d_ws, size_t ws_size,
                              hipStream_t stream) {
    const float* v    = (const float*)d_in[0];
    const float* k    = (const float*)d_in[1];
    const float* q    = (const float*)d_in[2];
    const float* mask = (const float*)d_in[3];
    const float* Wq   = (const float*)d_in[4];
    const float* bq   = (const float*)d_in[5];
    const float* Wk   = (const float*)d_in[6];
    const float* bk   = (const float*)d_in[7];
    const float* Wv   = (const float*)d_in[8];
    const float* bv   = (const float*)d_in[9];
    const float* Wf   = (const float*)d_in[10];
    const float* bf   = (const float*)d_in[11];
    float* out = (float*)d_out;

    char* ws = (char*)d_ws;
    size_t off = 0;
    short* Yq   = (short*)(ws + off); off += (size_t)BS * HD * 2;   // 16 MB
    short* Yk   = (short*)(ws + off); off += (size_t)BS * HD * 2;   // 16 MB
    short* Vt   = (short*)(ws + off); off += (size_t)BS * HD * 2;   // 16 MB
    float* Aout = (float*)(ws + off); off += (size_t)BS * HD * 4;   // 33.5 MB
    short* WTq  = (short*)(ws + off); off += (size_t)HD * DD * 2;
    short* WTk  = (short*)(ws + off); off += (size_t)HD * DD * 2;
    short* WTv  = (short*)(ws + off); off += (size_t)HD * DD * 2;
    short* Wfhi = (short*)(ws + off); off += (size_t)DD * HD * 2;
    short* Wflo = (short*)(ws + off); off += (size_t)DD * HD * 2;

    prep_wt<<<dim3(2048, 3), 128, 0, stream>>>(Wq, Wk, Wv, WTq, WTk, WTv);
    prep_wf<<<dim3(128), 256, 0, stream>>>(Wf, Wfhi, Wflo);
    proj_kernel<<<dim3(2048, 3), 256, 0, stream>>>(q, k, v, WTq, WTk, WTv,
                                                   bq, bk, bv, Yq, Yk, Vt);
    attn_kernel<<<dim3(128, 4, 2), 256, 0, stream>>>(Yq, Yk, Vt, mask, Aout);
    final_gemm<<<dim3(512), 256, 0, stream>>>(Aout, Wfhi, Wflo, bf, out);
}

// Round 3
// 314.386 us; speedup vs baseline: 2.3212x; 2.0714x over previous
//
#include <hip/hip_runtime.h>
#include <hip/hip_bf16.h>

#define SS 2048
#define DD 128
#define HH 16
#define BB 2
#define HD 2048   // H*D
#define BS 4096   // B*S

typedef __attribute__((ext_vector_type(4))) float f32x4;
typedef __attribute__((ext_vector_type(8))) short s16x8;

__device__ __forceinline__ short f2bf(float f) {
    union { __hip_bfloat16 h; short s; } u;
    u.h = __float2bfloat16(f);
    return u.s;
}
__device__ __forceinline__ float bf2f(short s) {
    union { unsigned u; float f; } w;
    w.u = ((unsigned)(unsigned short)s) << 16;
    return w.f;
}

// ---- prep: transpose+convert Wq/Wk/Wv [128][2048] -> WT bf16 [2048][128]
__global__ void prep_wt(const float* __restrict__ Wq, const float* __restrict__ Wk,
                        const float* __restrict__ Wv, short* __restrict__ WTq,
                        short* __restrict__ WTk, short* __restrict__ WTv) {
    int c = blockIdx.x;            // 0..2047
    int z = blockIdx.y;            // 0..2
    const float* W = (z==0) ? Wq : (z==1) ? Wk : Wv;
    short* WT      = (z==0) ? WTq : (z==1) ? WTk : WTv;
    int k = threadIdx.x;           // 0..127
    WT[c*DD + k] = f2bf(W[k*HD + c]);
}

// ---- prep: Wf [2048][128] -> WfT hi/lo bf16 [128][2048]
__global__ void prep_wf(const float* __restrict__ Wf, short* __restrict__ Whi,
                        short* __restrict__ Wlo) {
    int j = blockIdx.x;            // 0..127
    for (int k = threadIdx.x; k < HD; k += blockDim.x) {
        float v = Wf[k*DD + j];
        short hb = f2bf(v);
        Whi[j*HD + k] = hb;
        Wlo[j*HD + k] = f2bf(v - bf2f(hb));
    }
}

// ---- QKV projections. Each wave: 16 rows x 128 cols (8 col-tiles share A-frags).
__global__ __launch_bounds__(256) void proj_kernel(
    const float* __restrict__ Xq, const float* __restrict__ Xk, const float* __restrict__ Xv,
    const short* __restrict__ WTq, const short* __restrict__ WTk, const short* __restrict__ WTv,
    const float* __restrict__ bq, const float* __restrict__ bk, const float* __restrict__ bv,
    short* __restrict__ Yq, short* __restrict__ Yk, short* __restrict__ Vt)
{
    int z = blockIdx.y;
    const float* X  = (z==0) ? Xq  : (z==1) ? Xk  : Xv;
    const short* WT = (z==0) ? WTq : (z==1) ? WTk : WTv;
    const float* bias = (z==0) ? bq : (z==1) ? bk : bv;
    const float oscale = (z==0) ? 0.022097086912079608f : 1.0f;  // 1/sqrt(2048)

    int wave = threadIdx.x >> 6;
    int lane = threadIdx.x & 63;
    int lr = lane & 15, lg = lane >> 4;
    int bx = blockIdx.x;              // 0..1023
    int rb = bx >> 4;                 // 0..63
    int cb = bx & 15;                 // 0..15
    int row0 = rb * 64 + wave * 16;
    int col0 = cb * 128;

    s16x8 afr[4];
    const float* xrow = X + (size_t)(row0 + lr) * DD + lg * 8;
    #pragma unroll
    for (int c = 0; c < 4; ++c) {
        #pragma unroll
        for (int j = 0; j < 8; ++j) afr[c][j] = f2bf(xrow[c*32 + j]);
    }

    f32x4 acc[8];
    #pragma unroll
    for (int tn2 = 0; tn2 < 8; ++tn2) {
        acc[tn2] = (f32x4){0.f, 0.f, 0.f, 0.f};
        const short* wrow = WT + (size_t)(col0 + tn2*16 + lr) * DD + lg * 8;
        #pragma unroll
        for (int c = 0; c < 4; ++c) {
            s16x8 bfr = *reinterpret_cast<const s16x8*>(wrow + c*32);
            acc[tn2] = __builtin_amdgcn_mfma_f32_16x16x32_bf16(afr[c], bfr, acc[tn2], 0, 0, 0);
        }
    }

    if (z < 2) {
        short* Y = (z==0) ? Yq : Yk;
        #pragma unroll
        for (int tn2 = 0; tn2 < 8; ++tn2) {
            float bcol = bias[col0 + tn2*16 + lr];
            #pragma unroll
            for (int r = 0; r < 4; ++r) {
                int row = row0 + lg*4 + r;
                Y[(size_t)row * HD + col0 + tn2*16 + lr] = f2bf((acc[tn2][r] + bcol) * oscale);
            }
        }
    } else {
        #pragma unroll
        for (int tn2 = 0; tn2 < 8; ++tn2) {
            float bcol = bias[col0 + tn2*16 + lr];
            #pragma unroll
            for (int r = 0; r < 4; ++r) {
                int row = row0 + lg*4 + r;               // 0..4095
                int bb = row >> 11;                      // batch
                int f  = (row & 2047) * HD + col0 + tn2*16 + lr;
                int hh = f >> 18;                        // /(S*D)
                int rem = f & 262143;
                int s = rem >> 7, d = rem & 127;
                Vt[((size_t)((bb*HH + hh)*DD + d)) * SS + s] = f2bf(acc[tn2][r] + bcol);
            }
        }
    }
}

// ---- fused attention: 512-thread block = 8 waves = one head x 256 q-rows.
//      K/V tiles (KVBLK=64) staged in swizzled LDS, shared by all waves.
//      Reg-staged prefetch of next tile; flash online softmax; QBLK=32/wave.
__global__ __launch_bounds__(512, 2) void attn_kernel(
    const short* __restrict__ Yq, const short* __restrict__ Yk, const short* __restrict__ Vt,
    const float* __restrict__ mask, float* __restrict__ Aout)
{
    __shared__ alignas(16) char Kl[64 * 256];      // 16 KB  (64 k-rows x 128 d bf16, swizzled)
    __shared__ alignas(16) char Vl[128 * 128];     // 16 KB  (128 d-rows x 64 s bf16, swizzled)
    __shared__ alignas(16) char Pl[8][32 * 128];   // 32 KB  (per-wave P: 32 q x 64 k bf16, swizzled)

    const int tid = threadIdx.x;
    const int wave = tid >> 6, lane = tid & 63;
    const int lr = lane & 15, lg = lane >> 4;
    const int h = blockIdx.y, b = blockIdx.z;
    const int q0w = blockIdx.x * 256 + wave * 32;

    const short* Qb = Yq + (size_t)(b*HH + h) * (SS*DD);
    const short* Kb = Yk + (size_t)(b*HH + h) * (SS*DD);
    const short* Vb = Vt + (size_t)(b*HH + h) * (SS*DD);
    const float* Mb = mask + (size_t)b * SS * SS;

    // --- staging geometry (per thread: 2 K chunks + 2 V chunks of 16B) ---
    const int krow0 = tid >> 4, kc16 = tid & 15;           // K rows 0..31 (+32)
    const int kdst0 = krow0*256 + ((kc16 ^ (krow0 & 15)) << 4);
    const int kdst1 = kdst0 + 32*256;                       // (row+32)&15 == row&15
    const int vd0 = tid >> 3, vc8 = tid & 7;                // V d-rows 0..63 (+64)
    const int vdst0 = vd0*128 + ((vc8 ^ (vd0 & 7)) << 4);
    const int vdst1 = vdst0 + 64*128;                       // (d+64)&7 == d&7
    const short* ksrc0 = Kb + (size_t)krow0 * DD + kc16*8;
    const short* ksrc1 = Kb + (size_t)(krow0+32) * DD + kc16*8;
    const short* vsrc0 = Vb + (size_t)vd0 * SS + vc8*8;
    const short* vsrc1 = Vb + (size_t)(vd0+64) * SS + vc8*8;

    // --- Q fragments (held in regs; Yq pre-scaled by 1/sqrt(S)) ---
    s16x8 qf[2][4];
    #pragma unroll
    for (int rt = 0; rt < 2; ++rt) {
        const short* qrow = Qb + (size_t)(q0w + rt*16 + lr) * DD + lg * 8;
        #pragma unroll
        for (int c = 0; c < 4; ++c) qf[rt][c] = *reinterpret_cast<const s16x8*>(qrow + c*32);
    }

    f32x4 o[2][8];
    #pragma unroll
    for (int rt = 0; rt < 2; ++rt)
        #pragma unroll
        for (int dt = 0; dt < 8; ++dt) o[rt][dt] = (f32x4){0.f, 0.f, 0.f, 0.f};
    float mrun[2][4], lsum[2][4];
    #pragma unroll
    for (int rt = 0; rt < 2; ++rt)
        #pragma unroll
        for (int r = 0; r < 4; ++r) { mrun[rt][r] = -1e30f; lsum[rt][r] = 0.f; }

    // --- prologue: stage tile 0 ---
    {
        int4 ka  = *reinterpret_cast<const int4*>(ksrc0);
        int4 kb2 = *reinterpret_cast<const int4*>(ksrc1);
        int4 va  = *reinterpret_cast<const int4*>(vsrc0);
        int4 vb2 = *reinterpret_cast<const int4*>(vsrc1);
        *reinterpret_cast<int4*>(Kl + kdst0) = ka;
        *reinterpret_cast<int4*>(Kl + kdst1) = kb2;
        *reinterpret_cast<int4*>(Vl + vdst0) = va;
        *reinterpret_cast<int4*>(Vl + vdst1) = vb2;
    }
    __syncthreads();

    char* pw = Pl[wave];
    const int swr = (lr & 7) << 4;

    for (int kt = 0; kt < 32; ++kt) {
        const int kp0 = kt * 64;
        const int kpn = (kt < 31) ? kp0 + 64 : kp0;   // clamp (re-stage same, harmless)

        // issue next-tile staging loads (consumed after post-PV barrier)
        int4 ka  = *reinterpret_cast<const int4*>(ksrc0 + (size_t)kpn * DD);
        int4 kb2 = *reinterpret_cast<const int4*>(ksrc1 + (size_t)kpn * DD);
        int4 va  = *reinterpret_cast<const int4*>(vsrc0 + kpn);
        int4 vb2 = *reinterpret_cast<const int4*>(vsrc1 + kpn);

        // mask loads (consumed after QK^T)
        float mv[2][4][4];
        #pragma unroll
        for (int rt = 0; rt < 2; ++rt)
            #pragma unroll
            for (int t = 0; t < 4; ++t)
                #pragma unroll
                for (int r = 0; r < 4; ++r)
                    mv[rt][t][r] = Mb[(size_t)(q0w + rt*16 + lg*4 + r) * SS + kp0 + t*16 + lr];

        // QK^T: K frags from LDS (read once, shared across both row-tiles)
        f32x4 st[2][4];
        #pragma unroll
        for (int rt = 0; rt < 2; ++rt)
            #pragma unroll
            for (int t = 0; t < 4; ++t) st[rt][t] = (f32x4){0.f, 0.f, 0.f, 0.f};
        __builtin_amdgcn_s_setprio(1);
        #pragma unroll
        for (int t = 0; t < 4; ++t) {
            s16x8 kf[4];
            #pragma unroll
            for (int c = 0; c < 4; ++c)
                kf[c] = *reinterpret_cast<const s16x8*>(
                    Kl + (t*16 + lr)*256 + (((c*4 + lg) ^ lr) << 4));
            #pragma unroll
            for (int rt = 0; rt < 2; ++rt)
                #pragma unroll
                for (int c = 0; c < 4; ++c)
                    st[rt][t] = __builtin_amdgcn_mfma_f32_16x16x32_bf16(qf[rt][c], kf[c], st[rt][t], 0, 0, 0);
        }
        __builtin_amdgcn_s_setprio(0);

        // mask-mul + online softmax per row-tile
        float corr[2][4];
        #pragma unroll
        for (int rt = 0; rt < 2; ++rt) {
            #pragma unroll
            for (int r = 0; r < 4; ++r) {
                #pragma unroll
                for (int t = 0; t < 4; ++t) st[rt][t][r] *= mv[rt][t][r];
                float tmax = fmaxf(fmaxf(st[rt][0][r], st[rt][1][r]), fmaxf(st[rt][2][r], st[rt][3][r]));
                #pragma unroll
                for (int x = 8; x >= 1; x >>= 1) tmax = fmaxf(tmax, __shfl_xor(tmax, x, 16));
                float nm = fmaxf(mrun[rt][r], tmax);
                corr[rt][r] = __expf(mrun[rt][r] - nm);
                float psum = 0.f;
                #pragma unroll
                for (int t = 0; t < 4; ++t) { st[rt][t][r] = __expf(st[rt][t][r] - nm); psum += st[rt][t][r]; }
                #pragma unroll
                for (int x = 8; x >= 1; x >>= 1) psum += __shfl_xor(psum, x, 16);
                lsum[rt][r] = lsum[rt][r] * corr[rt][r] + psum;
                mrun[rt][r] = nm;
            }
            #pragma unroll
            for (int dt = 0; dt < 8; ++dt)
                #pragma unroll
                for (int r = 0; r < 4; ++r) o[rt][dt][r] *= corr[rt][r];
        }

        // P -> per-wave LDS (WAR: prior kt's P reads must drain first)
        asm volatile("s_waitcnt lgkmcnt(0)" ::: "memory");
        __builtin_amdgcn_sched_barrier(0);
        #pragma unroll
        for (int rt = 0; rt < 2; ++rt) {
            #pragma unroll
            for (int r = 0; r < 4; ++r) {
                int prow = rt*16 + lg*4 + r;
                int sw = (prow & 7) << 4;
                char* rp = pw + prow * 128;
                #pragma unroll
                for (int t = 0; t < 4; ++t)
                    *reinterpret_cast<short*>(rp + ((((t*16 + lr) << 1)) ^ sw)) = f2bf(st[rt][t][r]);
            }
        }
        asm volatile("s_waitcnt lgkmcnt(0)" ::: "memory");
        __builtin_amdgcn_sched_barrier(0);
        s16x8 pfr[2][2];
        #pragma unroll
        for (int rt = 0; rt < 2; ++rt)
            #pragma unroll
            for (int c2 = 0; c2 < 2; ++c2)
                pfr[rt][c2] = *reinterpret_cast<const s16x8*>(
                    pw + (rt*16 + lr)*128 + ((c2*64 + lg*16) ^ swr));

        // PV: V frags read once, shared across both row-tiles
        __builtin_amdgcn_s_setprio(1);
        #pragma unroll
        for (int dt = 0; dt < 8; ++dt) {
            const char* vbase = Vl + (dt*16 + lr)*128;
            s16x8 vf0 = *reinterpret_cast<const s16x8*>(vbase + (((0*4 + lg) ^ (lr & 7)) << 4));
            s16x8 vf1 = *reinterpret_cast<const s16x8*>(vbase + (((1*4 + lg) ^ (lr & 7)) << 4));
            #pragma unroll
            for (int rt = 0; rt < 2; ++rt) {
                o[rt][dt] = __builtin_amdgcn_mfma_f32_16x16x32_bf16(pfr[rt][0], vf0, o[rt][dt], 0, 0, 0);
                o[rt][dt] = __builtin_amdgcn_mfma_f32_16x16x32_bf16(pfr[rt][1], vf1, o[rt][dt], 0, 0, 0);
            }
        }
        __builtin_amdgcn_s_setprio(0);

        __syncthreads();                    // all waves done reading Kl/Vl
        *reinterpret_cast<int4*>(Kl + kdst0) = ka;
        *reinterpret_cast<int4*>(Kl + kdst1) = kb2;
        *reinterpret_cast<int4*>(Vl + vdst0) = va;
        *reinterpret_cast<int4*>(Vl + vdst1) = vb2;
        __syncthreads();                    // next tile visible
    }

    #pragma unroll
    for (int rt = 0; rt < 2; ++rt) {
        float* orow = Aout + ((size_t)(b*HH + h) * SS + q0w + rt*16) * DD;
        #pragma unroll
        for (int r = 0; r < 4; ++r) {
            float inv = 1.0f / lsum[rt][r];
            #pragma unroll
            for (int dt = 0; dt < 8; ++dt)
                orow[(size_t)(lg*4 + r) * DD + dt*16 + lr] = o[rt][dt][r] * inv;
        }
    }
}

// ---- final GEMM: out[4096][128] = A[4096][2048] @ Wf + bf, hi/lo bf16 split (~fp32 acc)
__global__ __launch_bounds__(256) void final_gemm(
    const float* __restrict__ A, const short* __restrict__ Whi, const short* __restrict__ Wlo,
    const float* __restrict__ bfv, float* __restrict__ out)
{
    int wave = threadIdx.x >> 6, lane = threadIdx.x & 63;
    int lr = lane & 15, lg = lane >> 4;
    int tile = blockIdx.x * 4 + wave;   // 0..2047
    int tm = tile >> 3;                 // 0..255
    int tn = tile & 7;                  // 0..7
    int row0 = tm * 16, col0 = tn * 16;

    f32x4 acc = {0.f, 0.f, 0.f, 0.f};
    const float* arow = A + (size_t)(row0 + lr) * HD + lg * 8;
    const short* whrow = Whi + (size_t)(col0 + lr) * HD + lg * 8;
    const short* wlrow = Wlo + (size_t)(col0 + lr) * HD + lg * 8;
    for (int kc = 0; kc < HD/32; ++kc) {
        s16x8 ah, al;
        #pragma unroll
        for (int j = 0; j < 8; ++j) {
            float v = arow[kc*32 + j];
            short hb = f2bf(v);
            ah[j] = hb;
            al[j] = f2bf(v - bf2f(hb));
        }
        s16x8 bh = *reinterpret_cast<const s16x8*>(whrow + kc*32);
        s16x8 bl = *reinterpret_cast<const s16x8*>(wlrow + kc*32);
        acc = __builtin_amdgcn_mfma_f32_16x16x32_bf16(ah, bh, acc, 0, 0, 0);
        acc = __builtin_amdgcn_mfma_f32_16x16x32_bf16(ah, bl, acc, 0, 0, 0);
        acc = __builtin_amdgcn_mfma_f32_16x16x32_bf16(al, bh, acc, 0, 0, 0);
    }
    float bc = bfv[col0 + lr];
    #pragma unroll
    for (int r = 0; r < 4; ++r) {
        out[(size_t)(row0 + lg*4 + r) * DD + col0 + lr] = acc[r] + bc;
    }
}

extern "C" void kernel_launch(void* const* d_in, const int* in_sizes, int n_in,
                              void* d_out, int out_size, void* d_ws, size_t ws_size,
                              hipStream_t stream) {
    const float* v    = (const float*)d_in[0];
    const float* k    = (const float*)d_in[1];
    const float* q    = (const float*)d_in[2];
    const float* mask = (const float*)d_in[3];
    const float* Wq   = (const float*)d_in[4];
    const float* bq   = (const float*)d_in[5];
    const float* Wk   = (const float*)d_in[6];
    const float* bk   = (const float*)d_in[7];
    const float* Wv   = (const float*)d_in[8];
    const float* bv   = (const float*)d_in[9];
    const float* Wf   = (const float*)d_in[10];
    const float* bf   = (const float*)d_in[11];
    float* out = (float*)d_out;

    char* ws = (char*)d_ws;
    size_t off = 0;
    short* Yq   = (short*)(ws + off); off += (size_t)BS * HD * 2;   // 16 MB
    short* Yk   = (short*)(ws + off); off += (size_t)BS * HD * 2;   // 16 MB
    short* Vt   = (short*)(ws + off); off += (size_t)BS * HD * 2;   // 16 MB
    float* Aout = (float*)(ws + off); off += (size_t)BS * HD * 4;   // 33.5 MB
    short* WTq  = (short*)(ws + off); off += (size_t)HD * DD * 2;
    short* WTk  = (short*)(ws + off); off += (size_t)HD * DD * 2;
    short* WTv  = (short*)(ws + off); off += (size_t)HD * DD * 2;
    short* Wfhi = (short*)(ws + off); off += (size_t)DD * HD * 2;
    short* Wflo = (short*)(ws + off); off += (size_t)DD * HD * 2;

    prep_wt<<<dim3(2048, 3), 128, 0, stream>>>(Wq, Wk, Wv, WTq, WTk, WTv);
    prep_wf<<<dim3(128), 256, 0, stream>>>(Wf, Wfhi, Wflo);
    proj_kernel<<<dim3(1024, 3), 256, 0, stream>>>(q, k, v, WTq, WTk, WTv,
                                                   bq, bk, bv, Yq, Yk, Vt);
    attn_kernel<<<dim3(8, 16, 2), 512, 0, stream>>>(Yq, Yk, Vt, mask, Aout);
    final_gemm<<<dim3(512), 256, 0, stream>>>(Aout, Wfhi, Wflo, bf, out);
}